// Round 7
// baseline (1336.716 us; speedup 1.0000x reference)
//
#include <hip/hip_runtime.h>

#define HID 256
#define OBS 1024
#define SEQ 50
#define BATCH 32
#define SO (SEQ*OBS)   // 51200
#define NBLK 256
#define NTHR 256

#define F_TRANSA   1
#define F_NEGID    2
#define F_ACC      4
#define F_TRANSB   8
#define F_SCALECOL 16

struct DevWS {
  float ub[2][HID][HID];     // 0,1  normalized reflectors (bitrev order)
  float Mm[2][HID][HID];     // 2,3  M = 2(I+2L)^-1, lower triangular
  float C2[2][HID][HID];     // 4,5  reflector Gram
  float ZT[2][HID][HID];     // 6,7  ZT = M @ ub
  float U[HID][HID];         // 8
  float V[HID][HID];         // 9
  float A[HID][HID];         // 10
  float A2[HID][HID];        // 11
  float A4[HID][HID];        // 12
  float A8[HID][HID];        // 13
  float A16[HID][HID];       // 14
  float A32[HID][HID];       // 15
  float Cg[HID][HID];        // 16  C^T C
  float G2[HID][HID];        // 17
  float Grun[HID][HID];      // 18
  float T[HID][HID];         // 19
  float T2[HID][HID];        // 20
  float G18[HID][HID];       // 21
  float G32b[HID][HID];      // 22
  float Gfin[HID][HID];      // 23
  float Zt4[SEQ][4][HID*BATCH];   // partial C^T Y_t per obs-quarter
  float Rb[2][25][HID*BATCH];     // 25,26 R-tree ping-pong
  float psum[NBLK+1];             // y^2 per block, logdet^2 at [NBLK]
  float s1b[BATCH];               // per-rhs sum alpha_j*rz_j
};
__device__ DevWS g;

// ---- software grid barrier state (self-cleaning: always 0 between barriers) ----
__device__ unsigned bar_in  = 0;
__device__ unsigned bar_out = 0;

__device__ __forceinline__ void gridbar(){
  __threadfence();                 // flush this thread's writes (device scope)
  __syncthreads();
  if(threadIdx.x == 0){
    // phase 1: arrive
    atomicAdd(&bar_in, 1u);
    while(atomicAdd(&bar_in, 0u) < (unsigned)NBLK){ __builtin_amdgcn_s_sleep(2); }
    // phase 2: depart; last departer resets both counters
    unsigned v = atomicAdd(&bar_out, 1u);
    if(v == (unsigned)NBLK - 1u){
      atomicExch(&bar_in, 0u);     // reset bar_in BEFORE releasing bar_out
      atomicExch(&bar_out, 0u);
    } else {
      while(atomicAdd(&bar_out, 0u) != 0u){ __builtin_amdgcn_s_sleep(2); }
    }
  }
  __syncthreads();
  __threadfence();                 // acquire: invalidate stale cached lines
}

__device__ __forceinline__ float* sel(int c){
  switch(c){
    case 0:  return &g.ub[0][0][0];
    case 1:  return &g.ub[1][0][0];
    case 2:  return &g.Mm[0][0][0];
    case 3:  return &g.Mm[1][0][0];
    case 4:  return &g.C2[0][0][0];
    case 5:  return &g.C2[1][0][0];
    case 6:  return &g.ZT[0][0][0];
    case 7:  return &g.ZT[1][0][0];
    case 8:  return &g.U[0][0];
    case 9:  return &g.V[0][0];
    case 10: return &g.A[0][0];
    case 11: return &g.A2[0][0];
    case 12: return &g.A4[0][0];
    case 13: return &g.A8[0][0];
    case 14: return &g.A16[0][0];
    case 15: return &g.A32[0][0];
    case 16: return &g.Cg[0][0];
    case 17: return &g.G2[0][0];
    case 18: return &g.Grun[0][0];
    case 19: return &g.T[0][0];
    case 20: return &g.T2[0][0];
    case 21: return &g.G18[0][0];
    case 22: return &g.G32b[0][0];
    case 23: return &g.Gfin[0][0];
    case 25: return &g.Rb[0][0][0];
    default: return &g.Rb[1][0][0];
  }
}

__device__ __forceinline__ int bitrev8(int x){
  x = ((x & 0x55) << 1) | ((x >> 1) & 0x55);
  x = ((x & 0x33) << 2) | ((x >> 2) & 0x33);
  x = ((x & 0x0F) << 4) | ((x >> 4) & 0x0F);
  return x;
}

// 256-thread block reduction; all threads get result. Uses sm[0..3].
__device__ __forceinline__ float blkred(float v, float* sm){
  v += __shfl_down(v,32); v += __shfl_down(v,16); v += __shfl_down(v,8);
  v += __shfl_down(v,4);  v += __shfl_down(v,2);  v += __shfl_down(v,1);
  const int t = threadIdx.x;
  if((t&63)==0) sm[t>>6] = v;
  __syncthreads();
  float r = sm[0]+sm[1]+sm[2]+sm[3];
  __syncthreads();
  return r;
}

// ---------- 32x32-tile GEMM unit over 256x256x256 ----------
__device__ void sq_tile(float* sm, int cA,int cB,int cC,int cD,int flags,int local,
                        const float* __restrict__ alpha){
  const float* A = sel(cA);
  const float* B = sel(cB);
  float* Cp = sel(cC);
  const float* Dp = sel(cD);
  float* As = sm; float* Bs = sm + 576;
  const int t = threadIdx.x, tx = t&15, ty = t>>4;
  const int m0 = (local>>3)*32, n0 = (local&7)*32;
  float a00=0.f,a01=0.f,a10=0.f,a11=0.f;
  for(int k0=0;k0<HID;k0+=16){
    if(flags & F_TRANSA){
      int kk=t>>4, mm=(t&15)*2;
      float2 a=*reinterpret_cast<const float2*>(&A[(k0+kk)*HID+m0+mm]);
      As[kk*36+mm]=a.x; As[kk*36+mm+1]=a.y;
    } else {
      int r=t>>3, c=(t&7)*2;
      float2 a=*reinterpret_cast<const float2*>(&A[(m0+r)*HID+k0+c]);
      As[c*36+r]=a.x; As[(c+1)*36+r]=a.y;
    }
    if(flags & F_TRANSB){
      int cb=t>>3, rb=(t&7)*2;
      float2 v=*reinterpret_cast<const float2*>(&B[(n0+cb)*HID+k0+rb]);
      Bs[rb*36+cb]=v.x; Bs[(rb+1)*36+cb]=v.y;
    } else {
      int rb=t>>4, cb=(t&15)*2;
      float2 bv=*reinterpret_cast<const float2*>(&B[(k0+rb)*HID+n0+cb]);
      Bs[rb*36+cb]=bv.x; Bs[rb*36+cb+1]=bv.y;
    }
    __syncthreads();
    #pragma unroll
    for(int kk=0;kk<16;kk++){
      float x0=As[kk*36+ty*2], x1=As[kk*36+ty*2+1];
      float y0=Bs[kk*36+tx*2], y1=Bs[kk*36+tx*2+1];
      a00+=x0*y0; a01+=x0*y1; a10+=x1*y0; a11+=x1*y1;
    }
    __syncthreads();
  }
  const int r=m0+ty*2, c=n0+tx*2;
  float v00=a00,v01=a01,v10=a10,v11=a11;
  if(flags & F_ACC){
    v00+=Dp[r*HID+c]; v01+=Dp[r*HID+c+1];
    v10+=Dp[(r+1)*HID+c]; v11+=Dp[(r+1)*HID+c+1];
  }
  if(flags & F_SCALECOL){
    float s0=1.f-fminf(fabsf(alpha[c]),1.f);
    float s1=1.f-fminf(fabsf(alpha[c+1]),1.f);
    v00*=s0; v01*=s1; v10*=s0; v11*=s1;
  }
  if(flags & F_NEGID){
    v00=((r==c)?1.f:0.f)-v00;   v01=((r==c+1)?1.f:0.f)-v01;
    v10=((r+1==c)?1.f:0.f)-v10; v11=((r+1==c+1)?1.f:0.f)-v11;
  }
  Cp[r*HID+c]=v00; Cp[r*HID+c+1]=v01;
  Cp[(r+1)*HID+c]=v10; Cp[(r+1)*HID+c+1]=v11;
}

// ---------- Cg = C^T C tile (K=1024) ----------
__device__ void cgram_tile(float* sm, int tile, const float* __restrict__ Cm){
  float* As = sm; float* Bs = sm + 576;
  const int t = threadIdx.x, tx = t&15, ty = t>>4;
  const int m0=(tile>>3)*32, n0=(tile&7)*32;
  float a00=0.f,a01=0.f,a10=0.f,a11=0.f;
  for(int o0=0;o0<OBS;o0+=16){
    int r=t>>4, cp=(t&15)*2;
    float2 a=*reinterpret_cast<const float2*>(&Cm[(o0+r)*HID+m0+cp]);
    As[r*36+cp]=a.x; As[r*36+cp+1]=a.y;
    float2 b2=*reinterpret_cast<const float2*>(&Cm[(o0+r)*HID+n0+cp]);
    Bs[r*36+cp]=b2.x; Bs[r*36+cp+1]=b2.y;
    __syncthreads();
    #pragma unroll
    for(int kk=0;kk<16;kk++){
      float x0=As[kk*36+ty*2], x1=As[kk*36+ty*2+1];
      float y0=Bs[kk*36+tx*2], y1=Bs[kk*36+tx*2+1];
      a00+=x0*y0; a01+=x0*y1; a10+=x1*y0; a11+=x1*y1;
    }
    __syncthreads();
  }
  g.Cg[m0+ty*2][n0+tx*2]=a00;   g.Cg[m0+ty*2][n0+tx*2+1]=a01;
  g.Cg[m0+ty*2+1][n0+tx*2]=a10; g.Cg[m0+ty*2+1][n0+tx*2+1]=a11;
}

// ---------- normalize one reflector row ----------
__device__ void norm_unit(float* sm, int u, const float* __restrict__ Up,
                          const float* __restrict__ Vp){
  int mat=u>>8, j=u&255, src=bitrev8(j);
  const float* P = mat ? Vp : Up;
  int t=threadIdx.x;
  float x = P[src*HID + t];
  float ss = blkred(x*x, sm);
  g.ub[mat][j][t] = x * rsqrtf(ss);
}

// ---------- CtY partial: Zt4[tt][ot] = C[ot-chunk]^T Y_t[ot-chunk] ----------
__device__ void cty_unit(float* sm, int u, const float* __restrict__ y,
                         const float* __restrict__ Cm){
  int tt=u>>2, ot=u&3;
  float* ys = sm;   // [256][36]
  const int t=threadIdx.x;
  for(int e=t;e<8192;e+=256){
    int b=e>>8, o=e&255;
    ys[o*36+b] = y[b*SO + tt*OBS + ot*256 + o];
  }
  __syncthreads();
  const int h=t;
  float acc[32];
  #pragma unroll
  for(int z=0;z<32;z++) acc[z]=0.f;
  for(int o=0;o<256;o++){
    float cv = Cm[(ot*256+o)*HID + h];
    #pragma unroll
    for(int bb=0;bb<32;bb+=4){
      float4 v=*reinterpret_cast<const float4*>(&ys[o*36+bb]);
      acc[bb]+=cv*v.x; acc[bb+1]+=cv*v.y; acc[bb+2]+=cv*v.z; acc[bb+3]+=cv*v.w;
    }
  }
  float* outp = &g.Zt4[tt][ot][h*BATCH];
  #pragma unroll
  for(int bb=0;bb<32;bb+=4){
    float4 w={acc[bb],acc[bb+1],acc[bb+2],acc[bb+3]};
    *reinterpret_cast<float4*>(&outp[bb])=w;
  }
  __syncthreads();
}

// ---------- M diag blocks: 32x32 forward substitution + zero row slice ----------
__device__ void mdiag_unit(float* sm, int u){
  int mat=u>>3, p=u&7;
  float* Ls = sm; // [32][33]
  const int t=threadIdx.x;
  for(int e=t;e<1024;e+=256){
    int k=e>>5, i=e&31;
    Ls[k*33+i] = g.C2[mat][p*32+k][p*32+i];
  }
  for(int e=t;e<32*256;e+=256){
    int r=e>>8, c=e&255;
    g.Mm[mat][p*32+r][c]=0.f;
  }
  __syncthreads();
  if(t<32){
    const int j=t;
    float m[32];
    #pragma unroll
    for(int k=0;k<32;k++){
      float s=0.f;
      #pragma unroll
      for(int i=0;i<32;i++) if(i<k) s += Ls[k*33+i]*m[i];
      m[k] = (k<j) ? 0.f : ((k==j) ? 2.f : (-2.f*s));
    }
    #pragma unroll
    for(int k=0;k<32;k++) g.Mm[mat][p*32+k][p*32+j]=m[k];
  }
  __syncthreads();
}

// ---------- merge level S: M21 = -M2 * G21 * M1 (one 32x32 out tile) ----------
template<int S>
__device__ void merge_unit(float* sm, int u){
  constexpr int NT = S/32;
  constexpr int NMG = 128/S;
  constexpr int NTILE = NT*NT;
  constexpr int STR = S/8;
  int mat = u/(NMG*NTILE);
  int rem = u%(NMG*NTILE);
  int mg = rem/NTILE;
  int tile = rem%NTILE;
  int tr = tile/NT, tc = tile%NT;
  const int o = mg*2*S;
  float* M2s = sm;                          // [32][S+1]
  float* Ts  = sm + 32*(S+1);               // [32][S+4]
  float* Gc  = sm + 32*(S+1) + 32*(S+4);    // [32][S+4] / [32][36]
  float* Mm = &g.Mm[mat][0][0];
  const float* C2m = &g.C2[mat][0][0];
  const int t=threadIdx.x;
  for(int e=t;e<32*S;e+=256){
    int r=e/S, k=e%S;
    M2s[r*(S+1)+k] = Mm[(o+S+tr*32+r)*HID + o+S+k];
  }
  __syncthreads();
  // T = M2_slice (32 x S) * G21 (S x S), k-chunks of 32
  const int r1=t>>3, jq=t&7;
  float acc[STR];
  #pragma unroll
  for(int z=0;z<STR;z++) acc[z]=0.f;
  for(int kc=0;kc<S;kc+=32){
    for(int e=t;e<32*S;e+=256){
      int kk=e/S, jj=e%S;
      Gc[kk*(S+4)+jj] = C2m[(o+S+kc+kk)*HID + o+jj];
    }
    __syncthreads();
    #pragma unroll
    for(int kk=0;kk<32;kk++){
      float mv = M2s[r1*(S+1)+kc+kk];
      #pragma unroll
      for(int z=0;z<STR;z++) acc[z] += mv * Gc[kk*(S+4)+jq*STR+z];
    }
    __syncthreads();
  }
  #pragma unroll
  for(int z=0;z<STR;z++) Ts[r1*(S+4)+jq*STR+z]=acc[z];
  __syncthreads();
  // out(32x32) = -T * M1[:, tc-slice], k-chunks of 32
  const int r2=t>>3, cq=t&7;
  float oacc[4]={0.f,0.f,0.f,0.f};
  for(int kc=0;kc<S;kc+=32){
    for(int e=t;e<1024;e+=256){
      int kk=e>>5, c=e&31;
      Gc[kk*36+c] = Mm[(o+kc+kk)*HID + o+tc*32+c];
    }
    __syncthreads();
    #pragma unroll
    for(int kk=0;kk<32;kk++){
      float tv = Ts[r2*(S+4)+kc+kk];
      #pragma unroll
      for(int z=0;z<4;z++) oacc[z] += tv * Gc[kk*36+cq*4+z];
    }
    __syncthreads();
  }
  #pragma unroll
  for(int z=0;z<4;z++)
    Mm[(o+S+tr*32+r2)*HID + o+tc*32+cq*4+z] = -oacc[z];
  __syncthreads();
}

// ---------- R-tree level unit ----------
template<int ZT4>
__device__ void rlevel_unit(float* sm, int cP, int cin, int cout, int npair, int local){
  const float* P = sel(cP);
  float* Out = sel(cout);
  const int t=threadIdx.x;
  const int j=local>>3, mt=local&7;
  const float* In = ZT4 ? nullptr : sel(cin);
  auto ldin = [&](int idx, int off)->float{
    if(ZT4){
      const float* z=&g.Zt4[idx][0][0];
      return z[off]+z[HID*BATCH+off]+z[2*HID*BATCH+off]+z[3*HID*BATCH+off];
    }
    return In[(size_t)idx*(HID*BATCH)+off];
  };
  if(j>=npair){
    for(int e=t;e<1024;e+=256)
      Out[(size_t)j*(HID*BATCH)+mt*1024+e] = ldin(2*j, mt*1024+e);
    return;
  }
  float* As=sm; float* Bs=sm+576;
  const int tx=t&15, ty=t>>4;
  const int m0=mt*32;
  float a00=0.f,a01=0.f,a10=0.f,a11=0.f;
  for(int k0=0;k0<HID;k0+=16){
    { int kk=t>>4, mm=(t&15)*2;
      float2 a=*reinterpret_cast<const float2*>(&P[(k0+kk)*HID+m0+mm]);
      As[kk*36+mm]=a.x; As[kk*36+mm+1]=a.y; }
    { int rb=t>>4, cb=(t&15)*2;
      Bs[rb*36+cb]  =ldin(2*j+1,(k0+rb)*BATCH+cb);
      Bs[rb*36+cb+1]=ldin(2*j+1,(k0+rb)*BATCH+cb+1); }
    __syncthreads();
    #pragma unroll
    for(int kk=0;kk<16;kk++){
      float p0=As[kk*36+ty*2], p1=As[kk*36+ty*2+1];
      float b0=Bs[kk*36+tx*2], b1=Bs[kk*36+tx*2+1];
      a00+=p0*b0; a01+=p0*b1; a10+=p1*b0; a11+=p1*b1;
    }
    __syncthreads();
  }
  float* C0 = Out + (size_t)j*(HID*BATCH);
  const int r=m0+ty*2, c=tx*2;
  C0[r*BATCH+c]      =ldin(2*j,r*BATCH+c)+a00;
  C0[r*BATCH+c+1]    =ldin(2*j,r*BATCH+c+1)+a01;
  C0[(r+1)*BATCH+c]  =ldin(2*j,(r+1)*BATCH+c)+a10;
  C0[(r+1)*BATCH+c+1]=ldin(2*j,(r+1)*BATCH+c+1)+a11;
}

// ---------- CG solve, one RHS per unit (256 threads) ----------
__device__ void cg_solve_unit(float* sm, int bb){
  float* ps = sm;          // [256]
  float* red = sm + 260;   // [4]
  const float* Gf = &g.Gfin[0][0];
  const int i = threadIdx.x;
  auto red256 = [&](float v)->float{
    v+=__shfl_down(v,32);v+=__shfl_down(v,16);v+=__shfl_down(v,8);
    v+=__shfl_down(v,4);v+=__shfl_down(v,2);v+=__shfl_down(v,1);
    if((i&63)==0) red[i>>6]=v;
    __syncthreads();
    float r=red[0]+red[1]+red[2]+red[3];
    __syncthreads();
    return r;
  };
  const float dinv = 1.f/Gf[i*(HID+1)];
  float rcur = g.Rb[1][0][i*BATCH+bb];
  ps[i] = dinv*rcur;
  __syncthreads();
  float rz = red256(dinv*rcur*rcur);
  float s1 = 0.f;
  for(int it=0; it<10; it++){
    float ap0=0.f,ap1=0.f,ap2=0.f,ap3=0.f;
    #pragma unroll 4
    for(int k=0;k<HID;k+=4){     // G symmetric: column reads are coalesced
      ap0 = fmaf(Gf[k*HID+i],     ps[k],   ap0);
      ap1 = fmaf(Gf[(k+1)*HID+i], ps[k+1], ap1);
      ap2 = fmaf(Gf[(k+2)*HID+i], ps[k+2], ap2);
      ap3 = fmaf(Gf[(k+3)*HID+i], ps[k+3], ap3);
    }
    float ap = (ap0+ap1)+(ap2+ap3);
    float pap = red256(ps[i]*ap);
    float al = rz/fmaxf(pap,1e-30f);
    rcur -= al*ap;
    float rzn = red256(dinv*rcur*rcur);
    s1 += al*rz;
    float be = rzn/fmaxf(rz,1e-30f);
    rz = rzn;
    __syncthreads();
    ps[i] = dinv*rcur + be*ps[i];
    __syncthreads();
  }
  if(i==0) g.s1b[bb]=s1;
  __syncthreads();
}

// =========================== the mono kernel ===========================
__global__ void __launch_bounds__(NTHR, 1)
k_mono(const float* __restrict__ y, const float* __restrict__ logdet,
       const float* __restrict__ Up, const float* __restrict__ Vp,
       const float* __restrict__ alpha, const float* __restrict__ Cm,
       float* __restrict__ out){
  __shared__ float sm[12800];   // 51.2 KB shared across all phase unit types
  const int b = blockIdx.x;
  const int t = threadIdx.x;

  // ---- P0: y^2 (all blocks) | norm(512) | Cg(64) | CtY(200) | logdet(1) ----
  {
    const float4* y4 = reinterpret_cast<const float4*>(y);
    float s=0.f;
    for(int i=b*NTHR+t; i<(BATCH*SO)/4; i+=NBLK*NTHR){
      float4 v=y4[i]; s+=v.x*v.x+v.y*v.y+v.z*v.z+v.w*v.w;
    }
    float r=blkred(s,sm);
    if(t==0) g.psum[b]=r;
    __syncthreads();
  }
  for(int u=b; u<777; u+=NBLK){
    if(u<512) norm_unit(sm,u,Up,Vp);
    else if(u<576) cgram_tile(sm,u-512,Cm);
    else if(u<776) cty_unit(sm,u-576,y,Cm);
    else {
      float s=0.f;
      for(int i=t;i<BATCH*SEQ;i+=256){float v=logdet[i]; s+=v*v;}
      float r=blkred(s,sm);
      if(t==0) g.psum[NBLK]=r;
      __syncthreads();
    }
  }
  gridbar();
  // ---- P1: C2 = ub ub^T (x2) ----
  for(int u=b;u<128;u+=NBLK){ int mat=u>>6; sq_tile(sm,mat,mat,4+mat,0,F_TRANSB,u&63,alpha); }
  gridbar();
  // ---- P2: M diag blocks ----
  for(int u=b;u<16;u+=NBLK) mdiag_unit(sm,u);
  gridbar();
  // ---- P3..P5: merge tree ----
  for(int u=b;u<8;u+=NBLK)  merge_unit<32>(sm,u);
  gridbar();
  for(int u=b;u<16;u+=NBLK) merge_unit<64>(sm,u);
  gridbar();
  for(int u=b;u<32;u+=NBLK) merge_unit<128>(sm,u);
  gridbar();
  // ---- P6: ZT = M ub ----
  for(int u=b;u<128;u+=NBLK){ int mat=u>>6; sq_tile(sm,2+mat,mat,6+mat,0,0,u&63,alpha); }
  gridbar();
  // ---- P7: U,V = I - ZT^T ub ----
  for(int u=b;u<128;u+=NBLK){ int mat=u>>6; sq_tile(sm,6+mat,mat,8+mat,0,F_TRANSA|F_NEGID,u&63,alpha); }
  gridbar();
  // ---- P8: A = (U V^T) * S ----
  for(int u=b;u<64;u+=NBLK) sq_tile(sm,8,9,10,0,F_TRANSB|F_SCALECOL,u,alpha);
  gridbar();
  // ---- P9: A2 ; T = A^T Cg ----
  for(int u=b;u<128;u+=NBLK){
    if(u<64) sq_tile(sm,10,10,11,0,0,u,alpha);
    else     sq_tile(sm,10,16,19,0,F_TRANSA,u-64,alpha);
  }
  gridbar();
  // ---- P10: G2 = Cg + T A ; A4 ; R1 (P=A, Zt4 -> Rb0, 25 pairs) ----
  for(int u=b;u<328;u+=NBLK){
    if(u<64)       sq_tile(sm,19,10,17,16,F_ACC,u,alpha);
    else if(u<128) sq_tile(sm,11,11,12,0,0,u-64,alpha);
    else           rlevel_unit<1>(sm,10,0,25,25,u-128);
  }
  gridbar();
  // ---- P11: T = A2^T G2 ; A8 ; R2 (P=A2, Rb0->Rb1, 12 pairs of 25) ----
  for(int u=b;u<232;u+=NBLK){
    if(u<64)       sq_tile(sm,11,17,19,0,F_TRANSA,u,alpha);
    else if(u<128) sq_tile(sm,12,12,13,0,0,u-64,alpha);
    else           rlevel_unit<0>(sm,11,25,26,12,u-128);
  }
  gridbar();
  // ---- P12: G4 = G2 + T A2 ; A16 ; R3 (P=A4, Rb1->Rb0, 6 pairs of 13) ----
  for(int u=b;u<184;u+=NBLK){
    if(u<64)       sq_tile(sm,19,11,18,17,F_ACC,u,alpha);
    else if(u<128) sq_tile(sm,13,13,14,0,0,u-64,alpha);
    else           rlevel_unit<0>(sm,12,26,25,6,u-128);
  }
  gridbar();
  // ---- P13: T = A4^T G4 ; A32 ; R4 (P=A8, Rb0->Rb1, 3 pairs of 7) ----
  for(int u=b;u<160;u+=NBLK){
    if(u<64)       sq_tile(sm,12,18,19,0,F_TRANSA,u,alpha);
    else if(u<128) sq_tile(sm,14,14,15,0,0,u-64,alpha);
    else           rlevel_unit<0>(sm,13,25,26,3,u-128);
  }
  gridbar();
  // ---- P14: G8 = G4 + T A4 ; R5 (P=A16, Rb1->Rb0, 2 pairs of 4) ----
  for(int u=b;u<80;u+=NBLK){
    if(u<64) sq_tile(sm,19,12,18,18,F_ACC,u,alpha);
    else     rlevel_unit<0>(sm,14,26,25,2,u-64);
  }
  gridbar();
  // ---- P15: T = A8^T G8 ; R6 (P=A32, Rb0->Rb1, 1 pair of 2) ----
  for(int u=b;u<72;u+=NBLK){
    if(u<64) sq_tile(sm,13,18,19,0,F_TRANSA,u,alpha);
    else     rlevel_unit<0>(sm,15,25,26,1,u-64);
  }
  gridbar();
  // ---- P16: G16 = G8 + T A8 ----
  for(int u=b;u<64;u+=NBLK) sq_tile(sm,19,13,18,18,F_ACC,u,alpha);
  gridbar();
  // ---- P17: T = A16^T G16 ; T2 = A16^T G2 ----
  for(int u=b;u<128;u+=NBLK){
    if(u<64) sq_tile(sm,14,18,19,0,F_TRANSA,u,alpha);
    else     sq_tile(sm,14,17,20,0,F_TRANSA,u-64,alpha);
  }
  gridbar();
  // ---- P18: G32 = G16 + T A16 ; G18 = G16 + T2 A16 ----
  for(int u=b;u<128;u+=NBLK){
    if(u<64) sq_tile(sm,19,14,22,18,F_ACC,u,alpha);
    else     sq_tile(sm,20,14,21,18,F_ACC,u-64,alpha);
  }
  gridbar();
  // ---- P19: T = A32^T G18 ----
  for(int u=b;u<64;u+=NBLK) sq_tile(sm,15,21,19,0,F_TRANSA,u,alpha);
  gridbar();
  // ---- P20: Gfin = G32 + T A32 ----
  for(int u=b;u<64;u+=NBLK) sq_tile(sm,19,15,23,22,F_ACC,u,alpha);
  gridbar();
  // ---- P21: CG (32 independent RHS) ----
  for(int u=b;u<BATCH;u+=NBLK) cg_solve_unit(sm,u);
  gridbar();
  // ---- P22: final loss ----
  if(b==0){
    float r = blkred(g.psum[t], sm);
    if(t==0){
      float t1=0.f;
      for(int q=0;q<BATCH;q++) t1+=g.s1b[q];
      float sld = g.psum[NBLK];
      float mw = (r - t1)/(float)(SO*BATCH);
      out[0] = 0.5f*mw + sld/((float)(BATCH*SEQ)*(float)OBS*(float)OBS);
    }
  }
}

extern "C" void kernel_launch(void* const* d_in, const int* in_sizes, int n_in,
                              void* d_out, int out_size, void* d_ws, size_t ws_size,
                              hipStream_t stream){
  const float* y      = (const float*)d_in[0];
  const float* logdet = (const float*)d_in[1];
  const float* Up     = (const float*)d_in[2];
  const float* Vp     = (const float*)d_in[3];
  const float* alpha  = (const float*)d_in[4];
  const float* Cm     = (const float*)d_in[5];
  float* outp = (float*)d_out;

  k_mono<<<dim3(NBLK), dim3(NTHR), 0, stream>>>(y, logdet, Up, Vp, alpha, Cm, outp);
}

// Round 9
// 1118.238 us; speedup vs baseline: 1.1954x; 1.1954x over previous
//
#include <hip/hip_runtime.h>

#define HID 256
#define OBS 1024
#define SEQ 50
#define BATCH 32
#define SO (SEQ*OBS)   // 51200
#define NBLK 256
#define NTHR 256

#define F_TRANSA   1
#define F_NEGID    2
#define F_ACC      4
#define F_TRANSB   8
#define F_SCALECOL 16

struct DevWS {
  float ub[2][HID][HID];     // 0,1  normalized reflectors (bitrev order)
  float Mm[2][HID][HID];     // 2,3  M = 2(I+2L)^-1, lower triangular
  float C2[2][HID][HID];     // 4,5  reflector Gram
  float ZT[2][HID][HID];     // 6,7  ZT = M @ ub
  float U[HID][HID];         // 8
  float V[HID][HID];         // 9
  float A[HID][HID];         // 10
  float A2[HID][HID];        // 11
  float A4[HID][HID];        // 12
  float A8[HID][HID];        // 13
  float A16[HID][HID];       // 14
  float A32[HID][HID];       // 15
  float Cg[HID][HID];        // 16  C^T C
  float G2[HID][HID];        // 17
  float Grun[HID][HID];      // 18
  float T[HID][HID];         // 19
  float T2[HID][HID];        // 20
  float G18[HID][HID];       // 21
  float G32b[HID][HID];      // 22
  float Gfin[HID][HID];      // 23
  float Zt4[SEQ][4][HID*BATCH];   // partial C^T Y_t per obs-quarter
  float Rb[2][25][HID*BATCH];     // 25,26 R-tree ping-pong
  float psum[NBLK+1];             // y^2 per block, logdet^2 at [NBLK]
  float s1b[BATCH];               // per-rhs sum alpha_j*rz_j
};
__device__ DevWS g;

// ---- sense-reversing grid barrier: one RMW per block, read-only polling ----
__device__ __align__(128) unsigned bar_cnt = 0;
__device__ __align__(128) unsigned bar_gen = 0;

__device__ __forceinline__ void gridbar(){
  __threadfence();                 // release: prior writes device-visible
  __syncthreads();
  if(threadIdx.x == 0){
    unsigned gen = __hip_atomic_load(&bar_gen, __ATOMIC_RELAXED, __HIP_MEMORY_SCOPE_AGENT);
    unsigned v = __hip_atomic_fetch_add(&bar_cnt, 1u, __ATOMIC_ACQ_REL, __HIP_MEMORY_SCOPE_AGENT);
    if(v == (unsigned)NBLK - 1u){
      // reset counter BEFORE releasing the generation
      __hip_atomic_store(&bar_cnt, 0u, __ATOMIC_RELAXED, __HIP_MEMORY_SCOPE_AGENT);
      __hip_atomic_store(&bar_gen, gen + 1u, __ATOMIC_RELEASE, __HIP_MEMORY_SCOPE_AGENT);
    } else {
      int spin = 0;
      while(__hip_atomic_load(&bar_gen, __ATOMIC_RELAXED, __HIP_MEMORY_SCOPE_AGENT) == gen){
        if(spin < 8){ __builtin_amdgcn_s_sleep(4); }
        else        { __builtin_amdgcn_s_sleep(32); }
        ++spin;
      }
    }
  }
  __syncthreads();
  __threadfence();                 // acquire: drop stale cached lines
}

__device__ __forceinline__ float* sel(int c){
  switch(c){
    case 0:  return &g.ub[0][0][0];
    case 1:  return &g.ub[1][0][0];
    case 2:  return &g.Mm[0][0][0];
    case 3:  return &g.Mm[1][0][0];
    case 4:  return &g.C2[0][0][0];
    case 5:  return &g.C2[1][0][0];
    case 6:  return &g.ZT[0][0][0];
    case 7:  return &g.ZT[1][0][0];
    case 8:  return &g.U[0][0];
    case 9:  return &g.V[0][0];
    case 10: return &g.A[0][0];
    case 11: return &g.A2[0][0];
    case 12: return &g.A4[0][0];
    case 13: return &g.A8[0][0];
    case 14: return &g.A16[0][0];
    case 15: return &g.A32[0][0];
    case 16: return &g.Cg[0][0];
    case 17: return &g.G2[0][0];
    case 18: return &g.Grun[0][0];
    case 19: return &g.T[0][0];
    case 20: return &g.T2[0][0];
    case 21: return &g.G18[0][0];
    case 22: return &g.G32b[0][0];
    case 23: return &g.Gfin[0][0];
    case 25: return &g.Rb[0][0][0];
    default: return &g.Rb[1][0][0];
  }
}

__device__ __forceinline__ int bitrev8(int x){
  x = ((x & 0x55) << 1) | ((x >> 1) & 0x55);
  x = ((x & 0x33) << 2) | ((x >> 2) & 0x33);
  x = ((x & 0x0F) << 4) | ((x >> 4) & 0x0F);
  return x;
}

// 256-thread block reduction; all threads get result. Uses sm[0..3].
__device__ __forceinline__ float blkred(float v, float* sm){
  v += __shfl_down(v,32); v += __shfl_down(v,16); v += __shfl_down(v,8);
  v += __shfl_down(v,4);  v += __shfl_down(v,2);  v += __shfl_down(v,1);
  const int t = threadIdx.x;
  if((t&63)==0) sm[t>>6] = v;
  __syncthreads();
  float r = sm[0]+sm[1]+sm[2]+sm[3];
  __syncthreads();
  return r;
}

// ---------- 32x32-tile GEMM unit over 256x256x256 ----------
__device__ void sq_tile(float* sm, int cA,int cB,int cC,int cD,int flags,int local,
                        const float* __restrict__ alpha){
  const float* A = sel(cA);
  const float* B = sel(cB);
  float* Cp = sel(cC);
  const float* Dp = sel(cD);
  float* As = sm; float* Bs = sm + 576;
  const int t = threadIdx.x, tx = t&15, ty = t>>4;
  const int m0 = (local>>3)*32, n0 = (local&7)*32;
  float a00=0.f,a01=0.f,a10=0.f,a11=0.f;
  for(int k0=0;k0<HID;k0+=16){
    if(flags & F_TRANSA){
      int kk=t>>4, mm=(t&15)*2;
      float2 a=*reinterpret_cast<const float2*>(&A[(k0+kk)*HID+m0+mm]);
      As[kk*36+mm]=a.x; As[kk*36+mm+1]=a.y;
    } else {
      int r=t>>3, c=(t&7)*2;
      float2 a=*reinterpret_cast<const float2*>(&A[(m0+r)*HID+k0+c]);
      As[c*36+r]=a.x; As[(c+1)*36+r]=a.y;
    }
    if(flags & F_TRANSB){
      int cb=t>>3, rb=(t&7)*2;
      float2 v=*reinterpret_cast<const float2*>(&B[(n0+cb)*HID+k0+rb]);
      Bs[rb*36+cb]=v.x; Bs[(rb+1)*36+cb]=v.y;
    } else {
      int rb=t>>4, cb=(t&15)*2;
      float2 bv=*reinterpret_cast<const float2*>(&B[(k0+rb)*HID+n0+cb]);
      Bs[rb*36+cb]=bv.x; Bs[rb*36+cb+1]=bv.y;
    }
    __syncthreads();
    #pragma unroll
    for(int kk=0;kk<16;kk++){
      float x0=As[kk*36+ty*2], x1=As[kk*36+ty*2+1];
      float y0=Bs[kk*36+tx*2], y1=Bs[kk*36+tx*2+1];
      a00+=x0*y0; a01+=x0*y1; a10+=x1*y0; a11+=x1*y1;
    }
    __syncthreads();
  }
  const int r=m0+ty*2, c=n0+tx*2;
  float v00=a00,v01=a01,v10=a10,v11=a11;
  if(flags & F_ACC){
    v00+=Dp[r*HID+c]; v01+=Dp[r*HID+c+1];
    v10+=Dp[(r+1)*HID+c]; v11+=Dp[(r+1)*HID+c+1];
  }
  if(flags & F_SCALECOL){
    float s0=1.f-fminf(fabsf(alpha[c]),1.f);
    float s1=1.f-fminf(fabsf(alpha[c+1]),1.f);
    v00*=s0; v01*=s1; v10*=s0; v11*=s1;
  }
  if(flags & F_NEGID){
    v00=((r==c)?1.f:0.f)-v00;   v01=((r==c+1)?1.f:0.f)-v01;
    v10=((r+1==c)?1.f:0.f)-v10; v11=((r+1==c+1)?1.f:0.f)-v11;
  }
  Cp[r*HID+c]=v00; Cp[r*HID+c+1]=v01;
  Cp[(r+1)*HID+c]=v10; Cp[(r+1)*HID+c+1]=v11;
}

// ---------- Cg = C^T C tile (K=1024) ----------
__device__ void cgram_tile(float* sm, int tile, const float* __restrict__ Cm){
  float* As = sm; float* Bs = sm + 576;
  const int t = threadIdx.x, tx = t&15, ty = t>>4;
  const int m0=(tile>>3)*32, n0=(tile&7)*32;
  float a00=0.f,a01=0.f,a10=0.f,a11=0.f;
  for(int o0=0;o0<OBS;o0+=16){
    int r=t>>4, cp=(t&15)*2;
    float2 a=*reinterpret_cast<const float2*>(&Cm[(o0+r)*HID+m0+cp]);
    As[r*36+cp]=a.x; As[r*36+cp+1]=a.y;
    float2 b2=*reinterpret_cast<const float2*>(&Cm[(o0+r)*HID+n0+cp]);
    Bs[r*36+cp]=b2.x; Bs[r*36+cp+1]=b2.y;
    __syncthreads();
    #pragma unroll
    for(int kk=0;kk<16;kk++){
      float x0=As[kk*36+ty*2], x1=As[kk*36+ty*2+1];
      float y0=Bs[kk*36+tx*2], y1=Bs[kk*36+tx*2+1];
      a00+=x0*y0; a01+=x0*y1; a10+=x1*y0; a11+=x1*y1;
    }
    __syncthreads();
  }
  g.Cg[m0+ty*2][n0+tx*2]=a00;   g.Cg[m0+ty*2][n0+tx*2+1]=a01;
  g.Cg[m0+ty*2+1][n0+tx*2]=a10; g.Cg[m0+ty*2+1][n0+tx*2+1]=a11;
}

// ---------- normalize one reflector row ----------
__device__ void norm_unit(float* sm, int u, const float* __restrict__ Up,
                          const float* __restrict__ Vp){
  int mat=u>>8, j=u&255, src=bitrev8(j);
  const float* P = mat ? Vp : Up;
  int t=threadIdx.x;
  float x = P[src*HID + t];
  float ss = blkred(x*x, sm);
  g.ub[mat][j][t] = x * rsqrtf(ss);
}

// ---------- CtY partial: Zt4[tt][ot] = C[ot-chunk]^T Y_t[ot-chunk] ----------
__device__ void cty_unit(float* sm, int u, const float* __restrict__ y,
                         const float* __restrict__ Cm){
  int tt=u>>2, ot=u&3;
  float* ys = sm;   // [256][36]
  const int t=threadIdx.x;
  for(int e=t;e<8192;e+=256){
    int b=e>>8, o=e&255;
    ys[o*36+b] = y[b*SO + tt*OBS + ot*256 + o];
  }
  __syncthreads();
  const int h=t;
  float acc[32];
  #pragma unroll
  for(int z=0;z<32;z++) acc[z]=0.f;
  for(int o=0;o<256;o++){
    float cv = Cm[(ot*256+o)*HID + h];
    #pragma unroll
    for(int bb=0;bb<32;bb+=4){
      float4 v=*reinterpret_cast<const float4*>(&ys[o*36+bb]);
      acc[bb]+=cv*v.x; acc[bb+1]+=cv*v.y; acc[bb+2]+=cv*v.z; acc[bb+3]+=cv*v.w;
    }
  }
  float* outp = &g.Zt4[tt][ot][h*BATCH];
  #pragma unroll
  for(int bb=0;bb<32;bb+=4){
    float4 w={acc[bb],acc[bb+1],acc[bb+2],acc[bb+3]};
    *reinterpret_cast<float4*>(&outp[bb])=w;
  }
  __syncthreads();
}

// ---------- M diag blocks: 32x32 forward substitution + zero row slice ----------
__device__ void mdiag_unit(float* sm, int u){
  int mat=u>>3, p=u&7;
  float* Ls = sm; // [32][33]
  const int t=threadIdx.x;
  for(int e=t;e<1024;e+=256){
    int k=e>>5, i=e&31;
    Ls[k*33+i] = g.C2[mat][p*32+k][p*32+i];
  }
  for(int e=t;e<32*256;e+=256){
    int r=e>>8, c=e&255;
    g.Mm[mat][p*32+r][c]=0.f;
  }
  __syncthreads();
  if(t<32){
    const int j=t;
    float m[32];
    #pragma unroll
    for(int k=0;k<32;k++){
      float s=0.f;
      #pragma unroll
      for(int i=0;i<32;i++) if(i<k) s += Ls[k*33+i]*m[i];
      m[k] = (k<j) ? 0.f : ((k==j) ? 2.f : (-2.f*s));
    }
    #pragma unroll
    for(int k=0;k<32;k++) g.Mm[mat][p*32+k][p*32+j]=m[k];
  }
  __syncthreads();
}

// ---------- merge level S: M21 = -M2 * G21 * M1 (one 32x32 out tile) ----------
template<int S>
__device__ void merge_unit(float* sm, int u){
  constexpr int NT = S/32;
  constexpr int NMG = 128/S;
  constexpr int NTILE = NT*NT;
  constexpr int STR = S/8;
  int mat = u/(NMG*NTILE);
  int rem = u%(NMG*NTILE);
  int mg = rem/NTILE;
  int tile = rem%NTILE;
  int tr = tile/NT, tc = tile%NT;
  const int o = mg*2*S;
  float* M2s = sm;                          // [32][S+1]
  float* Ts  = sm + 32*(S+1);               // [32][S+4]
  float* Gc  = sm + 32*(S+1) + 32*(S+4);    // [32][S+4] / [32][36]
  float* Mm = &g.Mm[mat][0][0];
  const float* C2m = &g.C2[mat][0][0];
  const int t=threadIdx.x;
  for(int e=t;e<32*S;e+=256){
    int r=e/S, k=e%S;
    M2s[r*(S+1)+k] = Mm[(o+S+tr*32+r)*HID + o+S+k];
  }
  __syncthreads();
  // T = M2_slice (32 x S) * G21 (S x S), k-chunks of 32
  const int r1=t>>3, jq=t&7;
  float acc[STR];
  #pragma unroll
  for(int z=0;z<STR;z++) acc[z]=0.f;
  for(int kc=0;kc<S;kc+=32){
    for(int e=t;e<32*S;e+=256){
      int kk=e/S, jj=e%S;
      Gc[kk*(S+4)+jj] = C2m[(o+S+kc+kk)*HID + o+jj];
    }
    __syncthreads();
    #pragma unroll
    for(int kk=0;kk<32;kk++){
      float mv = M2s[r1*(S+1)+kc+kk];
      #pragma unroll
      for(int z=0;z<STR;z++) acc[z] += mv * Gc[kk*(S+4)+jq*STR+z];
    }
    __syncthreads();
  }
  #pragma unroll
  for(int z=0;z<STR;z++) Ts[r1*(S+4)+jq*STR+z]=acc[z];
  __syncthreads();
  // out(32x32) = -T * M1[:, tc-slice], k-chunks of 32
  const int r2=t>>3, cq=t&7;
  float oacc[4]={0.f,0.f,0.f,0.f};
  for(int kc=0;kc<S;kc+=32){
    for(int e=t;e<1024;e+=256){
      int kk=e>>5, c=e&31;
      Gc[kk*36+c] = Mm[(o+kc+kk)*HID + o+tc*32+c];
    }
    __syncthreads();
    #pragma unroll
    for(int kk=0;kk<32;kk++){
      float tv = Ts[r2*(S+4)+kc+kk];
      #pragma unroll
      for(int z=0;z<4;z++) oacc[z] += tv * Gc[kk*36+cq*4+z];
    }
    __syncthreads();
  }
  #pragma unroll
  for(int z=0;z<4;z++)
    Mm[(o+S+tr*32+r2)*HID + o+tc*32+cq*4+z] = -oacc[z];
  __syncthreads();
}

// ---------- R-tree level unit ----------
template<int ZT4>
__device__ void rlevel_unit(float* sm, int cP, int cin, int cout, int npair, int local){
  const float* P = sel(cP);
  float* Out = sel(cout);
  const int t=threadIdx.x;
  const int j=local>>3, mt=local&7;
  const float* In = ZT4 ? nullptr : sel(cin);
  auto ldin = [&](int idx, int off)->float{
    if(ZT4){
      const float* z=&g.Zt4[idx][0][0];
      return z[off]+z[HID*BATCH+off]+z[2*HID*BATCH+off]+z[3*HID*BATCH+off];
    }
    return In[(size_t)idx*(HID*BATCH)+off];
  };
  if(j>=npair){
    for(int e=t;e<1024;e+=256)
      Out[(size_t)j*(HID*BATCH)+mt*1024+e] = ldin(2*j, mt*1024+e);
    return;
  }
  float* As=sm; float* Bs=sm+576;
  const int tx=t&15, ty=t>>4;
  const int m0=mt*32;
  float a00=0.f,a01=0.f,a10=0.f,a11=0.f;
  for(int k0=0;k0<HID;k0+=16){
    { int kk=t>>4, mm=(t&15)*2;
      float2 a=*reinterpret_cast<const float2*>(&P[(k0+kk)*HID+m0+mm]);
      As[kk*36+mm]=a.x; As[kk*36+mm+1]=a.y; }
    { int rb=t>>4, cb=(t&15)*2;
      Bs[rb*36+cb]  =ldin(2*j+1,(k0+rb)*BATCH+cb);
      Bs[rb*36+cb+1]=ldin(2*j+1,(k0+rb)*BATCH+cb+1); }
    __syncthreads();
    #pragma unroll
    for(int kk=0;kk<16;kk++){
      float p0=As[kk*36+ty*2], p1=As[kk*36+ty*2+1];
      float b0=Bs[kk*36+tx*2], b1=Bs[kk*36+tx*2+1];
      a00+=p0*b0; a01+=p0*b1; a10+=p1*b0; a11+=p1*b1;
    }
    __syncthreads();
  }
  float* C0 = Out + (size_t)j*(HID*BATCH);
  const int r=m0+ty*2, c=tx*2;
  C0[r*BATCH+c]      =ldin(2*j,r*BATCH+c)+a00;
  C0[r*BATCH+c+1]    =ldin(2*j,r*BATCH+c+1)+a01;
  C0[(r+1)*BATCH+c]  =ldin(2*j,(r+1)*BATCH+c)+a10;
  C0[(r+1)*BATCH+c+1]=ldin(2*j,(r+1)*BATCH+c+1)+a11;
}

// ---------- CG solve, one RHS per unit (256 threads) ----------
__device__ void cg_solve_unit(float* sm, int bb){
  float* ps = sm;          // [256]
  float* red = sm + 260;   // [4]
  const float* Gf = &g.Gfin[0][0];
  const int i = threadIdx.x;
  auto red256 = [&](float v)->float{
    v+=__shfl_down(v,32);v+=__shfl_down(v,16);v+=__shfl_down(v,8);
    v+=__shfl_down(v,4);v+=__shfl_down(v,2);v+=__shfl_down(v,1);
    if((i&63)==0) red[i>>6]=v;
    __syncthreads();
    float r=red[0]+red[1]+red[2]+red[3];
    __syncthreads();
    return r;
  };
  const float dinv = 1.f/Gf[i*(HID+1)];
  float rcur = g.Rb[1][0][i*BATCH+bb];
  ps[i] = dinv*rcur;
  __syncthreads();
  float rz = red256(dinv*rcur*rcur);
  float s1 = 0.f;
  for(int it=0; it<10; it++){
    float ap0=0.f,ap1=0.f,ap2=0.f,ap3=0.f;
    #pragma unroll 4
    for(int k=0;k<HID;k+=4){     // G symmetric: column reads are coalesced
      ap0 = fmaf(Gf[k*HID+i],     ps[k],   ap0);
      ap1 = fmaf(Gf[(k+1)*HID+i], ps[k+1], ap1);
      ap2 = fmaf(Gf[(k+2)*HID+i], ps[k+2], ap2);
      ap3 = fmaf(Gf[(k+3)*HID+i], ps[k+3], ap3);
    }
    float ap = (ap0+ap1)+(ap2+ap3);
    float pap = red256(ps[i]*ap);
    float al = rz/fmaxf(pap,1e-30f);
    rcur -= al*ap;
    float rzn = red256(dinv*rcur*rcur);
    s1 += al*rz;
    float be = rzn/fmaxf(rz,1e-30f);
    rz = rzn;
    __syncthreads();
    ps[i] = dinv*rcur + be*ps[i];
    __syncthreads();
  }
  if(i==0) g.s1b[bb]=s1;
  __syncthreads();
}

// =========================== the mono kernel ===========================
__global__ void __launch_bounds__(NTHR, 1)
k_mono(const float* __restrict__ y, const float* __restrict__ logdet,
       const float* __restrict__ Up, const float* __restrict__ Vp,
       const float* __restrict__ alpha, const float* __restrict__ Cm,
       float* __restrict__ out){
  __shared__ float sm[12800];   // 51.2 KB shared across all phase unit types
  const int b = blockIdx.x;
  const int t = threadIdx.x;

  // ---- P0: y^2 (all blocks) | norm(512) | Cg(64) | CtY(200) | logdet(1) ----
  {
    const float4* y4 = reinterpret_cast<const float4*>(y);
    float s=0.f;
    for(int i=b*NTHR+t; i<(BATCH*SO)/4; i+=NBLK*NTHR){
      float4 v=y4[i]; s+=v.x*v.x+v.y*v.y+v.z*v.z+v.w*v.w;
    }
    float r=blkred(s,sm);
    if(t==0) g.psum[b]=r;
    __syncthreads();
  }
  for(int u=b; u<777; u+=NBLK){
    if(u<512) norm_unit(sm,u,Up,Vp);
    else if(u<576) cgram_tile(sm,u-512,Cm);
    else if(u<776) cty_unit(sm,u-576,y,Cm);
    else {
      float s=0.f;
      for(int i=t;i<BATCH*SEQ;i+=256){float v=logdet[i]; s+=v*v;}
      float r=blkred(s,sm);
      if(t==0) g.psum[NBLK]=r;
      __syncthreads();
    }
  }
  gridbar();
  // ---- P1: C2 = ub ub^T (x2) ----
  for(int u=b;u<128;u+=NBLK){ int mat=u>>6; sq_tile(sm,mat,mat,4+mat,0,F_TRANSB,u&63,alpha); }
  gridbar();
  // ---- P2: M diag blocks ----
  for(int u=b;u<16;u+=NBLK) mdiag_unit(sm,u);
  gridbar();
  // ---- P3..P5: merge tree ----
  for(int u=b;u<8;u+=NBLK)  merge_unit<32>(sm,u);
  gridbar();
  for(int u=b;u<16;u+=NBLK) merge_unit<64>(sm,u);
  gridbar();
  for(int u=b;u<32;u+=NBLK) merge_unit<128>(sm,u);
  gridbar();
  // ---- P6: ZT = M ub ----
  for(int u=b;u<128;u+=NBLK){ int mat=u>>6; sq_tile(sm,2+mat,mat,6+mat,0,0,u&63,alpha); }
  gridbar();
  // ---- P7: U,V = I - ZT^T ub ----
  for(int u=b;u<128;u+=NBLK){ int mat=u>>6; sq_tile(sm,6+mat,mat,8+mat,0,F_TRANSA|F_NEGID,u&63,alpha); }
  gridbar();
  // ---- P8: A = (U V^T) * S ----
  for(int u=b;u<64;u+=NBLK) sq_tile(sm,8,9,10,0,F_TRANSB|F_SCALECOL,u,alpha);
  gridbar();
  // ---- P9: A2 ; T = A^T Cg ----
  for(int u=b;u<128;u+=NBLK){
    if(u<64) sq_tile(sm,10,10,11,0,0,u,alpha);
    else     sq_tile(sm,10,16,19,0,F_TRANSA,u-64,alpha);
  }
  gridbar();
  // ---- P10: G2 = Cg + T A ; A4 ; R1 (P=A, Zt4 -> Rb0, 25 pairs) ----
  for(int u=b;u<328;u+=NBLK){
    if(u<64)       sq_tile(sm,19,10,17,16,F_ACC,u,alpha);
    else if(u<128) sq_tile(sm,11,11,12,0,0,u-64,alpha);
    else           rlevel_unit<1>(sm,10,0,25,25,u-128);
  }
  gridbar();
  // ---- P11: T = A2^T G2 ; A8 ; R2 (P=A2, Rb0->Rb1, 12 pairs of 25) ----
  for(int u=b;u<232;u+=NBLK){
    if(u<64)       sq_tile(sm,11,17,19,0,F_TRANSA,u,alpha);
    else if(u<128) sq_tile(sm,12,12,13,0,0,u-64,alpha);
    else           rlevel_unit<0>(sm,11,25,26,12,u-128);
  }
  gridbar();
  // ---- P12: G4 = G2 + T A2 ; A16 ; R3 (P=A4, Rb1->Rb0, 6 pairs of 13) ----
  for(int u=b;u<184;u+=NBLK){
    if(u<64)       sq_tile(sm,19,11,18,17,F_ACC,u,alpha);
    else if(u<128) sq_tile(sm,13,13,14,0,0,u-64,alpha);
    else           rlevel_unit<0>(sm,12,26,25,6,u-128);
  }
  gridbar();
  // ---- P13: T = A4^T G4 ; A32 ; R4 (P=A8, Rb0->Rb1, 3 pairs of 7) ----
  for(int u=b;u<160;u+=NBLK){
    if(u<64)       sq_tile(sm,12,18,19,0,F_TRANSA,u,alpha);
    else if(u<128) sq_tile(sm,14,14,15,0,0,u-64,alpha);
    else           rlevel_unit<0>(sm,13,25,26,3,u-128);
  }
  gridbar();
  // ---- P14: G8 = G4 + T A4 ; R5 (P=A16, Rb1->Rb0, 2 pairs of 4) ----
  for(int u=b;u<80;u+=NBLK){
    if(u<64) sq_tile(sm,19,12,18,18,F_ACC,u,alpha);
    else     rlevel_unit<0>(sm,14,26,25,2,u-64);
  }
  gridbar();
  // ---- P15: T = A8^T G8 ; R6 (P=A32, Rb0->Rb1, 1 pair of 2) ----
  for(int u=b;u<72;u+=NBLK){
    if(u<64) sq_tile(sm,13,18,19,0,F_TRANSA,u,alpha);
    else     rlevel_unit<0>(sm,15,25,26,1,u-64);
  }
  gridbar();
  // ---- P16: G16 = G8 + T A8 ----
  for(int u=b;u<64;u+=NBLK) sq_tile(sm,19,13,18,18,F_ACC,u,alpha);
  gridbar();
  // ---- P17: T = A16^T G16 ; T2 = A16^T G2 ----
  for(int u=b;u<128;u+=NBLK){
    if(u<64) sq_tile(sm,14,18,19,0,F_TRANSA,u,alpha);
    else     sq_tile(sm,14,17,20,0,F_TRANSA,u-64,alpha);
  }
  gridbar();
  // ---- P18: G32 = G16 + T A16 ; G18 = G16 + T2 A16 ----
  for(int u=b;u<128;u+=NBLK){
    if(u<64) sq_tile(sm,19,14,22,18,F_ACC,u,alpha);
    else     sq_tile(sm,20,14,21,18,F_ACC,u-64,alpha);
  }
  gridbar();
  // ---- P19: T = A32^T G18 ----
  for(int u=b;u<64;u+=NBLK) sq_tile(sm,15,21,19,0,F_TRANSA,u,alpha);
  gridbar();
  // ---- P20: Gfin = G32 + T A32 ----
  for(int u=b;u<64;u+=NBLK) sq_tile(sm,19,15,23,22,F_ACC,u,alpha);
  gridbar();
  // ---- P21: CG (32 independent RHS) ----
  for(int u=b;u<BATCH;u+=NBLK) cg_solve_unit(sm,u);
  gridbar();
  // ---- P22: final loss ----
  if(b==0){
    float r = blkred(g.psum[t], sm);
    if(t==0){
      float t1=0.f;
      for(int q=0;q<BATCH;q++) t1+=g.s1b[q];
      float sld = g.psum[NBLK];
      float mw = (r - t1)/(float)(SO*BATCH);
      out[0] = 0.5f*mw + sld/((float)(BATCH*SEQ)*(float)OBS*(float)OBS);
    }
  }
}

extern "C" void kernel_launch(void* const* d_in, const int* in_sizes, int n_in,
                              void* d_out, int out_size, void* d_ws, size_t ws_size,
                              hipStream_t stream){
  const float* y      = (const float*)d_in[0];
  const float* logdet = (const float*)d_in[1];
  const float* Up     = (const float*)d_in[2];
  const float* Vp     = (const float*)d_in[3];
  const float* alpha  = (const float*)d_in[4];
  const float* Cm     = (const float*)d_in[5];
  float* outp = (float*)d_out;

  k_mono<<<dim3(NBLK), dim3(NTHR), 0, stream>>>(y, logdet, Up, Vp, alpha, Cm, outp);
}